// Round 7
// baseline (232.101 us; speedup 1.0000x reference)
//
#include <hip/hip_runtime.h>

typedef unsigned int u32;
typedef unsigned long long u64;
typedef unsigned short u16;

#define DEV __device__ __forceinline__

// ---------- helpers ----------
DEV u16 f2bf(float x) {                      // fp32 -> bf16 RNE
  u32 u = __float_as_uint(x);
  u32 r = u + 0x7fffu + ((u >> 16) & 1u);
  return (u16)(r >> 16);
}
DEV float bflo(u32 d) { return __uint_as_float(d << 16); }
DEV float bfhi(u32 d) { return __uint_as_float(d & 0xffff0000u); }
DEV u64 sortable64(double f) {               // monotonic f64 -> u64
  long long b = __double_as_longlong(f);
  return (u64)b ^ (u64)((b >> 63) | (long long)0x8000000000000000ll);
}
// fp64 exact-selection distance (float products are exact in f64)
DEV double ddist(double qx, double qy, double qz, double qd2,
                 float mxf, float myf, float mzf) {
  double cx = (double)mxf, cy = (double)myf, cz = (double)mzf;
  double cd2 = cx * cx + cy * cy + cz * cz;
  double dot = cx * qx + cy * qy + cz * qz;
  return (qd2 + cd2) - 2.0 * dot;
}

#define NB 2
#define NN 8192
#define NC 128
#define KK 21
// screening metric: st = cd2 - 2*dot (fp32, qd2 dropped: per-query constant).
// fp32-vs-fp64 error ~2e-4 on these scales; MARGIN covers it so the fp64
// top-21 provably survives screening (R4-proven).
#define MARGIN 1e-3f
#define CT 2048
#define SCAP 192                             // survivor capacity per query

// ---------- K0: fold BN into weights ----------
__global__ __launch_bounds__(256) void k_prep(
    const float* __restrict__ Wf, const float* __restrict__ gf, const float* __restrict__ bf_,
    const float* __restrict__ mf, const float* __restrict__ vf,
    const float* __restrict__ Wg, const float* __restrict__ gg, const float* __restrict__ bg,
    const float* __restrict__ mg, const float* __restrict__ vg,
    u16* __restrict__ Wt, float* __restrict__ beta_f,
    float* __restrict__ Wgu, float* __restrict__ Wgv, float* __restrict__ beta_g) {
  int g = blockIdx.x * 256 + threadIdx.x;     // 0..32767
  int c = g >> 8, o = g & 255;
  float val;
  if (o < 128) {
    float inv = gf[o] / sqrtf(vf[o] + 1e-5f);
    val = inv * (Wf[o * 256 + c] - Wf[o * 256 + c + 128]);
  } else {
    int o2 = o - 128;
    float inv = gf[o2] / sqrtf(vf[o2] + 1e-5f);
    val = inv * Wf[o2 * 256 + c + 128];
  }
  Wt[c * 256 + o] = f2bf(val);
  if (g < 128) {
    float inv = gf[g] / sqrtf(vf[g] + 1e-5f);
    beta_f[g] = bf_[g] - mf[g] * inv;
  } else if (g < 256) {
    int oo = g - 128;
    float invg = gg[oo] / sqrtf(vg[oo] + 1e-5f);
#pragma unroll
    for (int d = 0; d < 3; ++d) {
      Wgu[oo * 3 + d] = invg * (Wg[oo * 6 + d] - Wg[oo * 6 + 3 + d]);
      Wgv[oo * 3 + d] = invg * Wg[oo * 6 + 3 + d];
    }
    beta_g[oo] = bg[oo] - mg[oo] * invg;
  }
}

// ---------- K1geo ----------
__global__ __launch_bounds__(256) void k_geo(
    const float* __restrict__ xyz, const float* __restrict__ Wgu, const float* __restrict__ Wgv,
    const float* __restrict__ beta_g, u32* __restrict__ ucat, u32* __restrict__ vcat) {
  int g = blockIdx.x * 256 + threadIdx.x;     // < 16384*64
  int p = g >> 6, oc = g & 63;
  const float* xp = xyz + p * 3;
  float X = xp[0], Y = xp[1], Z = xp[2];
  u32 du = 0, dv = 0;
#pragma unroll
  for (int h = 0; h < 2; ++h) {
    int o = oc * 2 + h;
    float ug = X * Wgu[o * 3] + Y * Wgu[o * 3 + 1] + Z * Wgu[o * 3 + 2] + beta_g[o];
    float vv = X * Wgv[o * 3] + Y * Wgv[o * 3 + 1] + Z * Wgv[o * 3 + 2];
    du |= (u32)f2bf(ug) << (16 * h);
    dv |= (u32)f2bf(vv) << (16 * h);
  }
  ucat[p * 128 + oc] = du;
  vcat[p * 128 + oc] = dv;
}

// ---------- K1f: feat branch GEMM ----------
__global__ __launch_bounds__(256) void k_feat(
    const float* __restrict__ f, const u32* __restrict__ Wt32, const float* __restrict__ beta_f,
    u32* __restrict__ ucat, u32* __restrict__ vcat) {
  __shared__ u32 sW[128 * 128];
  __shared__ float sF[128][68];

  const int t = threadIdx.x;
  const int b = blockIdx.x >> 7;
  const int n0 = (blockIdx.x & 127) << 6;
  const int boff = b * (NC * NN);

#pragma unroll
  for (int k = 0; k < 64; ++k) sW[t + (k << 8)] = Wt32[t + (k << 8)];
#pragma unroll
  for (int k = 0; k < 32; ++k) {
    int i = t + (k << 8);
    int c = i >> 6, col = i & 63;
    sF[c][col] = f[boff + c * NN + n0 + col];
  }
  __syncthreads();

  const int w = t >> 6, lane = t & 63;
  const int og = lane >> 3, pg = lane & 7;
  const int o0 = w * 64 + og * 8;
  const int p0 = pg * 8;

  float acc[8][8];
#pragma unroll
  for (int a = 0; a < 8; ++a)
#pragma unroll
    for (int p = 0; p < 8; ++p) acc[a][p] = 0.0f;

  for (int c = 0; c < 128; ++c) {
    float4 fa = *(const float4*)&sF[c][p0];
    float4 fb = *(const float4*)&sF[c][p0 + 4];
    uint4 wr = *(const uint4*)&sW[c * 128 + (o0 >> 1)];
    float wv[8] = {bflo(wr.x), bfhi(wr.x), bflo(wr.y), bfhi(wr.y),
                   bflo(wr.z), bfhi(wr.z), bflo(wr.w), bfhi(wr.w)};
    float fv[8] = {fa.x, fa.y, fa.z, fa.w, fb.x, fb.y, fb.z, fb.w};
#pragma unroll
    for (int a = 0; a < 8; ++a)
#pragma unroll
      for (int p = 0; p < 8; ++p) acc[a][p] = __builtin_fmaf(wv[a], fv[p], acc[a][p]);
  }

  const int ochan = o0 & 127;
  const bool is_u = (o0 < 128);
  float bet[8];
#pragma unroll
  for (int a = 0; a < 8; ++a) bet[a] = is_u ? beta_f[ochan + a] : 0.0f;
  u32* dstbase = is_u ? ucat : vcat;
#pragma unroll
  for (int p = 0; p < 8; ++p) {
    int pt = (b << 13) + n0 + p0 + p;
    u32 d0 = (u32)f2bf(acc[0][p] + bet[0]) | ((u32)f2bf(acc[1][p] + bet[1]) << 16);
    u32 d1 = (u32)f2bf(acc[2][p] + bet[2]) | ((u32)f2bf(acc[3][p] + bet[3]) << 16);
    u32 d2 = (u32)f2bf(acc[4][p] + bet[4]) | ((u32)f2bf(acc[5][p] + bet[5]) << 16);
    u32 d3 = (u32)f2bf(acc[6][p] + bet[6]) | ((u32)f2bf(acc[7][p] + bet[7]) << 16);
    *(uint4*)&dstbase[pt * 128 + 64 + (ochan >> 1)] = make_uint4(d0, d1, d2, d3);
  }
}

DEV u64 surv_key(const u16* __restrict__ srow, u32 cnt, int pos,
                 const float* __restrict__ X,
                 double Qx, double Qy, double Qz, double Qd2) {
  bool vv = (u32)pos < cnt;
  u32 m = vv ? (u32)srow[pos] : 0u;
  double ss = ddist(Qx, Qy, Qz, Qd2, X[m * 3], X[m * 3 + 1], X[m * 3 + 2]);
  return vv ? ((sortable64(ss) & 0xFFFFFFFFFFFFE000ull) | (u64)m) : ~0ull;
}

// 21st smallest of the wave's 64 values (disjoint-subset lane minima)
DEV float stat21(float v, int lane) {
#pragma unroll
  for (int k = 2; k <= 64; k <<= 1) {
#pragma unroll
    for (int j = k >> 1; j > 0; j >>= 1) {
      float p = __shfl_xor(v, j);
      bool takeMin = (((lane & k) == 0) == ((lane & j) == 0));
      v = takeMin ? fminf(v, p) : fmaxf(v, p);
    }
  }
  return __shfl(v, 20);
}

// ---------- K2: exact KNN (k=21) — single-scan subsample threshold ----------
// 16 queries/block, 4/wave. Threshold = 21st of 64 lane-minima over tile 0
// (subsample bound >= full-set d21 => valid), tightened after tiles 1,2 from
// accumulated minima (seen-set bound, still valid). One staging per tile.
// Selection exact fp64. LDS ~39 KB -> 4 blocks/CU.
__global__ __launch_bounds__(256, 4) void k_knn(const float* __restrict__ xyz,
                                                int* __restrict__ knn) {
  __shared__ float4 sc[CT];                   // 32 KB (x,y,z,d2)
  __shared__ u16 ssurv[16][SCAP];             // 6 KB
  __shared__ u32 scnt[16];

  const int t = threadIdx.x;
  const int blk = blockIdx.x;                 // 0..1023
  const int b = blk >> 9;
  const int n0 = (blk & 511) << 4;            // 16 queries/block
  const float* X = xyz + b * (NN * 3);

  if (t < 16) scnt[t] = 0u;

  const int w = t >> 6, lane = t & 63;

  float mx[4], my[4], mz[4];
#pragma unroll
  for (int i = 0; i < 4; ++i) {
    int q = n0 + (w << 2) + i;
    mx[i] = -2.0f * X[q * 3];
    my[i] = -2.0f * X[q * 3 + 1];
    mz[i] = -2.0f * X[q * 3 + 2];
  }

  float mn[4], thr[4];
#pragma unroll
  for (int i = 0; i < 4; ++i) mn[i] = __builtin_inff();

  // ---- stage tile 0 ----
  {
    const float4* g4 = (const float4*)X;
#pragma unroll
    for (int gix = 0; gix < 2; ++gix) {
      int g = t + (gix << 8);                 // group of 4 points
      float4 a = g4[g * 3], bb = g4[g * 3 + 1], c = g4[g * 3 + 2];
      float px[4] = {a.x, a.w, bb.z, c.y};
      float py[4] = {a.y, bb.x, bb.w, c.z};
      float pz[4] = {a.z, bb.y, c.x, c.w};
#pragma unroll
      for (int j = 0; j < 4; ++j) {
        float d2 = __builtin_fmaf(px[j], px[j], __builtin_fmaf(py[j], py[j], pz[j] * pz[j]));
        sc[(g << 2) + j] = make_float4(px[j], py[j], pz[j], d2);
      }
    }
  }
  __syncthreads();

  // ---- threshold pass over tile 0 (min only) ----
#pragma unroll 4
  for (int cc = 0; cc < CT; cc += 64) {
    float4 C = sc[cc + lane];
#pragma unroll
    for (int i = 0; i < 4; ++i) {
      float s = __builtin_fmaf(C.x, mx[i],
                __builtin_fmaf(C.y, my[i],
                __builtin_fmaf(C.z, mz[i], C.w)));
      mn[i] = fminf(mn[i], s);
    }
  }
#pragma unroll
  for (int i = 0; i < 4; ++i) thr[i] = stat21(mn[i], lane) + MARGIN;

  // ---- compact tile 0 (sc unchanged, no barrier needed) ----
#pragma unroll 4
  for (int cc = 0; cc < CT; cc += 64) {
    float4 C = sc[cc + lane];
    int mbase = cc + lane;
#pragma unroll
    for (int i = 0; i < 4; ++i) {
      float s = __builtin_fmaf(C.x, mx[i],
                __builtin_fmaf(C.y, my[i],
                __builtin_fmaf(C.z, mz[i], C.w)));
      if (s <= thr[i]) {
        int qq = (w << 2) + i;
        u32 slot = atomicAdd(&scnt[qq], 1u);
        if (slot < (u32)SCAP) ssurv[qq][slot] = (u16)mbase;
      }
    }
  }

  // ---- tiles 1..3: stage, fused min+compact, tighten after 1 and 2 ----
  for (int ct = 1; ct < NN / CT; ++ct) {
    __syncthreads();                          // all waves done with sc
    {
      const float4* g4 = (const float4*)(X + ct * (CT * 3));
#pragma unroll
      for (int gix = 0; gix < 2; ++gix) {
        int g = t + (gix << 8);
        float4 a = g4[g * 3], bb = g4[g * 3 + 1], c = g4[g * 3 + 2];
        float px[4] = {a.x, a.w, bb.z, c.y};
        float py[4] = {a.y, bb.x, bb.w, c.z};
        float pz[4] = {a.z, bb.y, c.x, c.w};
#pragma unroll
        for (int j = 0; j < 4; ++j) {
          float d2 = __builtin_fmaf(px[j], px[j], __builtin_fmaf(py[j], py[j], pz[j] * pz[j]));
          sc[(g << 2) + j] = make_float4(px[j], py[j], pz[j], d2);
        }
      }
    }
    __syncthreads();

    int tbase = ct * CT;
#pragma unroll 4
    for (int cc = 0; cc < CT; cc += 64) {
      float4 C = sc[cc + lane];
      int mbase = tbase + cc + lane;
#pragma unroll
      for (int i = 0; i < 4; ++i) {
        float s = __builtin_fmaf(C.x, mx[i],
                  __builtin_fmaf(C.y, my[i],
                  __builtin_fmaf(C.z, mz[i], C.w)));
        mn[i] = fminf(mn[i], s);
        if (s <= thr[i]) {
          int qq = (w << 2) + i;
          u32 slot = atomicAdd(&scnt[qq], 1u);
          if (slot < (u32)SCAP) ssurv[qq][slot] = (u16)mbase;
        }
      }
    }
    if (ct < 3) {                             // tighten (seen-set bound valid)
#pragma unroll
      for (int i = 0; i < 4; ++i) {
        float nt = stat21(mn[i], lane) + MARGIN;
        thr[i] = fminf(thr[i], nt);
      }
    }
  }
  __syncthreads();

  // ---- selection: exact top-21 by fp64 (dist, idx); wave w owns 4 rows ----
#pragma unroll 1
  for (int i = 0; i < 4; ++i) {
    const int qq = (w << 2) + i;
    const int q = n0 + qq;
    double Qx = (double)X[q * 3], Qy = (double)X[q * 3 + 1], Qz = (double)X[q * 3 + 2];
    double Qd2 = Qx * Qx + Qy * Qy + Qz * Qz;
    u32 cnt = scnt[qq]; if (cnt > (u32)SCAP) cnt = (u32)SCAP;
    const u16* srow = ssurv[qq];
    int* outp = knn + ((b << 13) + q) * KK;

    u64 k0 = surv_key(srow, cnt, lane, X, Qx, Qy, Qz, Qd2);

    if (cnt <= 64u) {
      u64 v = k0;
#pragma unroll
      for (int k = 2; k <= 64; k <<= 1) {
#pragma unroll
        for (int j = k >> 1; j > 0; j >>= 1) {
          u64 p = __shfl_xor(v, j);
          bool takeMin = (((lane & k) == 0) == ((lane & j) == 0));
          bool pl = p < v;
          u64 mnv = pl ? p : v;
          u64 mxv = pl ? v : p;
          v = takeMin ? mnv : mxv;
        }
      }
      if (lane < KK) outp[lane] = (int)(v & 8191ull);
    } else if (cnt <= 128u) {
      u64 k1 = surv_key(srow, cnt, lane + 64, X, Qx, Qy, Qz, Qd2);
      u32 selm = 0;
      for (int r = 0; r < KK; ++r) {
        u64 mk = (k0 < k1) ? k0 : k1;
#pragma unroll
        for (int j = 32; j > 0; j >>= 1) {
          u64 p = __shfl_xor(mk, j);
          if (p < mk) mk = p;
        }
        if (k0 == mk) k0 = ~0ull;
        else if (k1 == mk) k1 = ~0ull;
        if (lane == r) selm = (u32)(mk & 8191ull);
      }
      if (lane < KK) outp[lane] = (int)selm;
    } else {
      u64 k1 = surv_key(srow, cnt, lane + 64, X, Qx, Qy, Qz, Qd2);
      u64 k2 = surv_key(srow, cnt, lane + 128, X, Qx, Qy, Qz, Qd2);
      u32 selm = 0;
      for (int r = 0; r < KK; ++r) {
        u64 m01 = (k0 < k1) ? k0 : k1;
        u64 mk = (m01 < k2) ? m01 : k2;
#pragma unroll
        for (int j = 32; j > 0; j >>= 1) {
          u64 p = __shfl_xor(mk, j);
          if (p < mk) mk = p;
        }
        if (k0 == mk) k0 = ~0ull;
        else if (k1 == mk) k1 = ~0ull;
        else if (k2 == mk) k2 = ~0ull;
        if (lane == r) selm = (u32)(mk & 8191ull);
      }
      if (lane < KK) outp[lane] = (int)selm;
    }
  }
}

// ---------- K3: gather + max + relu + transpose-write ----------
__global__ __launch_bounds__(256) void k_gather(
    const u32* __restrict__ ucat, const u32* __restrict__ vcat,
    const int* __restrict__ knn, float* __restrict__ out) {
  __shared__ float tr[64 * 258];

  const int t = threadIdx.x;
  const int b = blockIdx.x >> 7;
  const int n0 = (blockIdx.x & 127) << 6;
  const int w = t >> 6, lane = t & 63;
  const int which = w >> 1;
  const int lo = ((w & 1) << 6) | lane;

  for (int step = 0; step < 32; ++step) {
    int qq = step * 2 + which;
    int q = n0 + qq;
    const int* ip = knn + ((b << 13) + q) * KK;
    float a0 = -__builtin_inff(), a1 = -__builtin_inff();
#pragma unroll
    for (int k = 0; k < KK; ++k) {
      int p = ip[k];
      u32 d = vcat[(((b << 13) + p) << 7) + lo];
      a0 = fmaxf(a0, bflo(d));
      a1 = fmaxf(a1, bfhi(d));
    }
    u32 u = ucat[(((b << 13) + q) << 7) + lo];
    float r0 = fmaxf(bflo(u) + a0, 0.0f);
    float r1 = fmaxf(bfhi(u) + a1, 0.0f);
    *(float2*)&tr[qq * 258 + 2 * lo] = make_float2(r0, r1);
  }
  __syncthreads();

  float* ob = out + b * (256 * NN);
  for (int i = 0; i < 64; ++i) {
    int o = (w << 6) + i;
    ob[o * NN + n0 + lane] = tr[lane * 258 + o];
  }
}

// ---------- launch ----------
extern "C" void kernel_launch(void* const* d_in, const int* in_sizes, int n_in,
                              void* d_out, int out_size, void* d_ws, size_t ws_size,
                              hipStream_t stream) {
  const float* xyz = (const float*)d_in[0];
  const float* f   = (const float*)d_in[1];
  const float* Wg  = (const float*)d_in[2];
  const float* gg  = (const float*)d_in[3];
  const float* bg  = (const float*)d_in[4];
  const float* mg  = (const float*)d_in[5];
  const float* vg  = (const float*)d_in[6];
  const float* Wf  = (const float*)d_in[7];
  const float* gf  = (const float*)d_in[8];
  const float* bf_ = (const float*)d_in[9];
  const float* mf  = (const float*)d_in[10];
  const float* vf  = (const float*)d_in[11];

  char* ws = (char*)d_ws;
  u16*   Wt     = (u16*)ws;                               // 65536 B
  float* beta_f = (float*)(ws + 65536);
  float* Wgu    = (float*)(ws + 66048);
  float* Wgv    = (float*)(ws + 67584);
  float* beta_g = (float*)(ws + 69120);
  u32*   ucat   = (u32*)(ws + 69632);                     // 8 MB
  u32*   vcat   = (u32*)(ws + 69632 + 8388608);           // 8 MB
  int*   knn    = (int*)(ws + 16846848);                  // 1.376 MB
  float* out    = (float*)d_out;

  if (ws_size < (size_t)(16846848 + 16384 * KK * 4)) return;

  k_prep<<<dim3(128), dim3(256), 0, stream>>>(Wf, gf, bf_, mf, vf, Wg, gg, bg, mg, vg,
                                              Wt, beta_f, Wgu, Wgv, beta_g);
  k_geo<<<dim3(4096), dim3(256), 0, stream>>>(xyz, Wgu, Wgv, beta_g, ucat, vcat);
  k_feat<<<dim3(256), dim3(256), 0, stream>>>(f, (const u32*)Wt, beta_f, ucat, vcat);
  k_knn<<<dim3(1024), dim3(256), 0, stream>>>(xyz, knn);
  k_gather<<<dim3(256), dim3(256), 0, stream>>>(ucat, vcat, knn, out);
}

// Round 8
// 228.878 us; speedup vs baseline: 1.0141x; 1.0141x over previous
//
#include <hip/hip_runtime.h>

typedef unsigned int u32;
typedef unsigned long long u64;
typedef unsigned short u16;

#define DEV __device__ __forceinline__

// ---------- helpers ----------
DEV u16 f2bf(float x) {                      // fp32 -> bf16 RNE
  u32 u = __float_as_uint(x);
  u32 r = u + 0x7fffu + ((u >> 16) & 1u);
  return (u16)(r >> 16);
}
DEV float bflo(u32 d) { return __uint_as_float(d << 16); }
DEV float bfhi(u32 d) { return __uint_as_float(d & 0xffff0000u); }
DEV u64 sortable64(double f) {               // monotonic f64 -> u64
  long long b = __double_as_longlong(f);
  return (u64)b ^ (u64)((b >> 63) | (long long)0x8000000000000000ll);
}
// fp64 exact-selection distance (float products are exact in f64)
DEV double ddist(double qx, double qy, double qz, double qd2,
                 float mxf, float myf, float mzf) {
  double cx = (double)mxf, cy = (double)myf, cz = (double)mzf;
  double cd2 = cx * cx + cy * cy + cz * cz;
  double dot = cx * qx + cy * qy + cz * qz;
  return (qd2 + cd2) - 2.0 * dot;
}

#define NB 2
#define NN 8192
#define NC 128
#define KK 21
// screening metric: st = cd2 - 2*dot (fp32, qd2 dropped: per-query constant).
// fp32-vs-fp64 error ~2e-4 on these scales; MARGIN covers it so the fp64
// top-21 provably survives screening (R4-proven).
#define MARGIN 1e-3f
#define CT 2048
#define SCAP 192                             // survivor capacity per query

// ---------- K0: fold BN into weights ----------
__global__ __launch_bounds__(256) void k_prep(
    const float* __restrict__ Wf, const float* __restrict__ gf, const float* __restrict__ bf_,
    const float* __restrict__ mf, const float* __restrict__ vf,
    const float* __restrict__ Wg, const float* __restrict__ gg, const float* __restrict__ bg,
    const float* __restrict__ mg, const float* __restrict__ vg,
    u16* __restrict__ Wt, float* __restrict__ beta_f,
    float* __restrict__ Wgu, float* __restrict__ Wgv, float* __restrict__ beta_g) {
  int g = blockIdx.x * 256 + threadIdx.x;     // 0..32767
  int c = g >> 8, o = g & 255;
  float val;
  if (o < 128) {
    float inv = gf[o] / sqrtf(vf[o] + 1e-5f);
    val = inv * (Wf[o * 256 + c] - Wf[o * 256 + c + 128]);
  } else {
    int o2 = o - 128;
    float inv = gf[o2] / sqrtf(vf[o2] + 1e-5f);
    val = inv * Wf[o2 * 256 + c + 128];
  }
  Wt[c * 256 + o] = f2bf(val);
  if (g < 128) {
    float inv = gf[g] / sqrtf(vf[g] + 1e-5f);
    beta_f[g] = bf_[g] - mf[g] * inv;
  } else if (g < 256) {
    int oo = g - 128;
    float invg = gg[oo] / sqrtf(vg[oo] + 1e-5f);
#pragma unroll
    for (int d = 0; d < 3; ++d) {
      Wgu[oo * 3 + d] = invg * (Wg[oo * 6 + d] - Wg[oo * 6 + 3 + d]);
      Wgv[oo * 3 + d] = invg * Wg[oo * 6 + 3 + d];
    }
    beta_g[oo] = bg[oo] - mg[oo] * invg;
  }
}

// ---------- K1geo ----------
__global__ __launch_bounds__(256) void k_geo(
    const float* __restrict__ xyz, const float* __restrict__ Wgu, const float* __restrict__ Wgv,
    const float* __restrict__ beta_g, u32* __restrict__ ucat, u32* __restrict__ vcat) {
  int g = blockIdx.x * 256 + threadIdx.x;     // < 16384*64
  int p = g >> 6, oc = g & 63;
  const float* xp = xyz + p * 3;
  float X = xp[0], Y = xp[1], Z = xp[2];
  u32 du = 0, dv = 0;
#pragma unroll
  for (int h = 0; h < 2; ++h) {
    int o = oc * 2 + h;
    float ug = X * Wgu[o * 3] + Y * Wgu[o * 3 + 1] + Z * Wgu[o * 3 + 2] + beta_g[o];
    float vv = X * Wgv[o * 3] + Y * Wgv[o * 3 + 1] + Z * Wgv[o * 3 + 2];
    du |= (u32)f2bf(ug) << (16 * h);
    dv |= (u32)f2bf(vv) << (16 * h);
  }
  ucat[p * 128 + oc] = du;
  vcat[p * 128 + oc] = dv;
}

// ---------- K1f: feat branch GEMM ----------
__global__ __launch_bounds__(256) void k_feat(
    const float* __restrict__ f, const u32* __restrict__ Wt32, const float* __restrict__ beta_f,
    u32* __restrict__ ucat, u32* __restrict__ vcat) {
  __shared__ u32 sW[128 * 128];
  __shared__ float sF[128][68];

  const int t = threadIdx.x;
  const int b = blockIdx.x >> 7;
  const int n0 = (blockIdx.x & 127) << 6;
  const int boff = b * (NC * NN);

#pragma unroll
  for (int k = 0; k < 64; ++k) sW[t + (k << 8)] = Wt32[t + (k << 8)];
#pragma unroll
  for (int k = 0; k < 32; ++k) {
    int i = t + (k << 8);
    int c = i >> 6, col = i & 63;
    sF[c][col] = f[boff + c * NN + n0 + col];
  }
  __syncthreads();

  const int w = t >> 6, lane = t & 63;
  const int og = lane >> 3, pg = lane & 7;
  const int o0 = w * 64 + og * 8;
  const int p0 = pg * 8;

  float acc[8][8];
#pragma unroll
  for (int a = 0; a < 8; ++a)
#pragma unroll
    for (int p = 0; p < 8; ++p) acc[a][p] = 0.0f;

  for (int c = 0; c < 128; ++c) {
    float4 fa = *(const float4*)&sF[c][p0];
    float4 fb = *(const float4*)&sF[c][p0 + 4];
    uint4 wr = *(const uint4*)&sW[c * 128 + (o0 >> 1)];
    float wv[8] = {bflo(wr.x), bfhi(wr.x), bflo(wr.y), bfhi(wr.y),
                   bflo(wr.z), bfhi(wr.z), bflo(wr.w), bfhi(wr.w)};
    float fv[8] = {fa.x, fa.y, fa.z, fa.w, fb.x, fb.y, fb.z, fb.w};
#pragma unroll
    for (int a = 0; a < 8; ++a)
#pragma unroll
      for (int p = 0; p < 8; ++p) acc[a][p] = __builtin_fmaf(wv[a], fv[p], acc[a][p]);
  }

  const int ochan = o0 & 127;
  const bool is_u = (o0 < 128);
  float bet[8];
#pragma unroll
  for (int a = 0; a < 8; ++a) bet[a] = is_u ? beta_f[ochan + a] : 0.0f;
  u32* dstbase = is_u ? ucat : vcat;
#pragma unroll
  for (int p = 0; p < 8; ++p) {
    int pt = (b << 13) + n0 + p0 + p;
    u32 d0 = (u32)f2bf(acc[0][p] + bet[0]) | ((u32)f2bf(acc[1][p] + bet[1]) << 16);
    u32 d1 = (u32)f2bf(acc[2][p] + bet[2]) | ((u32)f2bf(acc[3][p] + bet[3]) << 16);
    u32 d2 = (u32)f2bf(acc[4][p] + bet[4]) | ((u32)f2bf(acc[5][p] + bet[5]) << 16);
    u32 d3 = (u32)f2bf(acc[6][p] + bet[6]) | ((u32)f2bf(acc[7][p] + bet[7]) << 16);
    *(uint4*)&dstbase[pt * 128 + 64 + (ochan >> 1)] = make_uint4(d0, d1, d2, d3);
  }
}

DEV u64 surv_key(const u16* __restrict__ srow, u32 cnt, int pos,
                 const float* __restrict__ X,
                 double Qx, double Qy, double Qz, double Qd2) {
  bool vv = (u32)pos < cnt;
  u32 m = vv ? (u32)srow[pos] : 0u;
  double ss = ddist(Qx, Qy, Qz, Qd2, X[m * 3], X[m * 3 + 1], X[m * 3 + 2]);
  return vv ? ((sortable64(ss) & 0xFFFFFFFFFFFFE000ull) | (u64)m) : ~0ull;
}

// 21st smallest of the wave's 64 values (disjoint-subset lane minima)
DEV float stat21(float v, int lane) {
#pragma unroll
  for (int k = 2; k <= 64; k <<= 1) {
#pragma unroll
    for (int j = k >> 1; j > 0; j >>= 1) {
      float p = __shfl_xor(v, j);
      bool takeMin = (((lane & k) == 0) == ((lane & j) == 0));
      v = takeMin ? fminf(v, p) : fmaxf(v, p);
    }
  }
  return __shfl(v, 20);
}

// Staging: R4-proven conflict-free pattern — one float4 per lane per step,
// lane-contiguous 16B stride (R7's 64B/lane variant was a 32-way bank
// conflict: SQ_LDS_BANK_CONFLICT 18.9K -> 3.31M, k_knn 62.6 -> 103.6 us).
DEV void stage_tile(float4* __restrict__ sc, const float* __restrict__ Xt, int t) {
#pragma unroll
  for (int k = 0; k < 8; ++k) {
    int c = (k << 8) + t;
    float x = Xt[c * 3], y = Xt[c * 3 + 1], z = Xt[c * 3 + 2];
    float d2 = __builtin_fmaf(x, x, __builtin_fmaf(y, y, z * z));
    sc[c] = make_float4(x, y, z, d2);
  }
}

// ---------- K2: exact KNN (k=21) — single-scan subsample threshold ----------
// 16 queries/block, 4/wave. Threshold = 21st of 64 lane-minima over tile 0
// (subsample bound >= full-set d21 => valid), tightened after tiles 1,2 from
// accumulated minima (seen-set bound, still valid). One staging per tile.
// Selection exact fp64. LDS ~39 KB -> 4 blocks/CU.
__global__ __launch_bounds__(256, 4) void k_knn(const float* __restrict__ xyz,
                                                int* __restrict__ knn) {
  __shared__ float4 sc[CT];                   // 32 KB (x,y,z,d2)
  __shared__ u16 ssurv[16][SCAP];             // 6 KB
  __shared__ u32 scnt[16];

  const int t = threadIdx.x;
  const int blk = blockIdx.x;                 // 0..1023
  const int b = blk >> 9;
  const int n0 = (blk & 511) << 4;            // 16 queries/block
  const float* X = xyz + b * (NN * 3);

  if (t < 16) scnt[t] = 0u;

  const int w = t >> 6, lane = t & 63;

  float mx[4], my[4], mz[4];
#pragma unroll
  for (int i = 0; i < 4; ++i) {
    int q = n0 + (w << 2) + i;
    mx[i] = -2.0f * X[q * 3];
    my[i] = -2.0f * X[q * 3 + 1];
    mz[i] = -2.0f * X[q * 3 + 2];
  }

  float mn[4], thr[4];
#pragma unroll
  for (int i = 0; i < 4; ++i) mn[i] = __builtin_inff();

  // ---- stage tile 0 ----
  stage_tile(sc, X, t);
  __syncthreads();

  // ---- threshold pass over tile 0 (min only) ----
#pragma unroll 4
  for (int cc = 0; cc < CT; cc += 64) {
    float4 C = sc[cc + lane];
#pragma unroll
    for (int i = 0; i < 4; ++i) {
      float s = __builtin_fmaf(C.x, mx[i],
                __builtin_fmaf(C.y, my[i],
                __builtin_fmaf(C.z, mz[i], C.w)));
      mn[i] = fminf(mn[i], s);
    }
  }
#pragma unroll
  for (int i = 0; i < 4; ++i) thr[i] = stat21(mn[i], lane) + MARGIN;

  // ---- compact tile 0 (sc unchanged, no barrier needed) ----
#pragma unroll 4
  for (int cc = 0; cc < CT; cc += 64) {
    float4 C = sc[cc + lane];
    int mbase = cc + lane;
#pragma unroll
    for (int i = 0; i < 4; ++i) {
      float s = __builtin_fmaf(C.x, mx[i],
                __builtin_fmaf(C.y, my[i],
                __builtin_fmaf(C.z, mz[i], C.w)));
      if (s <= thr[i]) {
        int qq = (w << 2) + i;
        u32 slot = atomicAdd(&scnt[qq], 1u);
        if (slot < (u32)SCAP) ssurv[qq][slot] = (u16)mbase;
      }
    }
  }

  // ---- tiles 1..3: stage, fused min+compact, tighten after 1 and 2 ----
  for (int ct = 1; ct < NN / CT; ++ct) {
    __syncthreads();                          // all waves done with sc
    stage_tile(sc, X + ct * (CT * 3), t);
    __syncthreads();

    int tbase = ct * CT;
#pragma unroll 4
    for (int cc = 0; cc < CT; cc += 64) {
      float4 C = sc[cc + lane];
      int mbase = tbase + cc + lane;
#pragma unroll
      for (int i = 0; i < 4; ++i) {
        float s = __builtin_fmaf(C.x, mx[i],
                  __builtin_fmaf(C.y, my[i],
                  __builtin_fmaf(C.z, mz[i], C.w)));
        mn[i] = fminf(mn[i], s);
        if (s <= thr[i]) {
          int qq = (w << 2) + i;
          u32 slot = atomicAdd(&scnt[qq], 1u);
          if (slot < (u32)SCAP) ssurv[qq][slot] = (u16)mbase;
        }
      }
    }
    if (ct < 3) {                             // tighten (seen-set bound valid)
#pragma unroll
      for (int i = 0; i < 4; ++i) {
        float nt = stat21(mn[i], lane) + MARGIN;
        thr[i] = fminf(thr[i], nt);
      }
    }
  }
  __syncthreads();

  // ---- selection: exact top-21 by fp64 (dist, idx); wave w owns 4 rows ----
#pragma unroll 1
  for (int i = 0; i < 4; ++i) {
    const int qq = (w << 2) + i;
    const int q = n0 + qq;
    double Qx = (double)X[q * 3], Qy = (double)X[q * 3 + 1], Qz = (double)X[q * 3 + 2];
    double Qd2 = Qx * Qx + Qy * Qy + Qz * Qz;
    u32 cnt = scnt[qq]; if (cnt > (u32)SCAP) cnt = (u32)SCAP;
    const u16* srow = ssurv[qq];
    int* outp = knn + ((b << 13) + q) * KK;

    u64 k0 = surv_key(srow, cnt, lane, X, Qx, Qy, Qz, Qd2);

    if (cnt <= 64u) {
      u64 v = k0;
#pragma unroll
      for (int k = 2; k <= 64; k <<= 1) {
#pragma unroll
        for (int j = k >> 1; j > 0; j >>= 1) {
          u64 p = __shfl_xor(v, j);
          bool takeMin = (((lane & k) == 0) == ((lane & j) == 0));
          bool pl = p < v;
          u64 mnv = pl ? p : v;
          u64 mxv = pl ? v : p;
          v = takeMin ? mnv : mxv;
        }
      }
      if (lane < KK) outp[lane] = (int)(v & 8191ull);
    } else if (cnt <= 128u) {
      u64 k1 = surv_key(srow, cnt, lane + 64, X, Qx, Qy, Qz, Qd2);
      u32 selm = 0;
      for (int r = 0; r < KK; ++r) {
        u64 mk = (k0 < k1) ? k0 : k1;
#pragma unroll
        for (int j = 32; j > 0; j >>= 1) {
          u64 p = __shfl_xor(mk, j);
          if (p < mk) mk = p;
        }
        if (k0 == mk) k0 = ~0ull;
        else if (k1 == mk) k1 = ~0ull;
        if (lane == r) selm = (u32)(mk & 8191ull);
      }
      if (lane < KK) outp[lane] = (int)selm;
    } else {
      u64 k1 = surv_key(srow, cnt, lane + 64, X, Qx, Qy, Qz, Qd2);
      u64 k2 = surv_key(srow, cnt, lane + 128, X, Qx, Qy, Qz, Qd2);
      u32 selm = 0;
      for (int r = 0; r < KK; ++r) {
        u64 m01 = (k0 < k1) ? k0 : k1;
        u64 mk = (m01 < k2) ? m01 : k2;
#pragma unroll
        for (int j = 32; j > 0; j >>= 1) {
          u64 p = __shfl_xor(mk, j);
          if (p < mk) mk = p;
        }
        if (k0 == mk) k0 = ~0ull;
        else if (k1 == mk) k1 = ~0ull;
        else if (k2 == mk) k2 = ~0ull;
        if (lane == r) selm = (u32)(mk & 8191ull);
      }
      if (lane < KK) outp[lane] = (int)selm;
    }
  }
}

// ---------- K3: gather + max + relu + transpose-write ----------
__global__ __launch_bounds__(256) void k_gather(
    const u32* __restrict__ ucat, const u32* __restrict__ vcat,
    const int* __restrict__ knn, float* __restrict__ out) {
  __shared__ float tr[64 * 258];

  const int t = threadIdx.x;
  const int b = blockIdx.x >> 7;
  const int n0 = (blockIdx.x & 127) << 6;
  const int w = t >> 6, lane = t & 63;
  const int which = w >> 1;
  const int lo = ((w & 1) << 6) | lane;

  for (int step = 0; step < 32; ++step) {
    int qq = step * 2 + which;
    int q = n0 + qq;
    const int* ip = knn + ((b << 13) + q) * KK;
    float a0 = -__builtin_inff(), a1 = -__builtin_inff();
#pragma unroll
    for (int k = 0; k < KK; ++k) {
      int p = ip[k];
      u32 d = vcat[(((b << 13) + p) << 7) + lo];
      a0 = fmaxf(a0, bflo(d));
      a1 = fmaxf(a1, bfhi(d));
    }
    u32 u = ucat[(((b << 13) + q) << 7) + lo];
    float r0 = fmaxf(bflo(u) + a0, 0.0f);
    float r1 = fmaxf(bfhi(u) + a1, 0.0f);
    *(float2*)&tr[qq * 258 + 2 * lo] = make_float2(r0, r1);
  }
  __syncthreads();

  float* ob = out + b * (256 * NN);
  for (int i = 0; i < 64; ++i) {
    int o = (w << 6) + i;
    ob[o * NN + n0 + lane] = tr[lane * 258 + o];
  }
}

// ---------- launch ----------
extern "C" void kernel_launch(void* const* d_in, const int* in_sizes, int n_in,
                              void* d_out, int out_size, void* d_ws, size_t ws_size,
                              hipStream_t stream) {
  const float* xyz = (const float*)d_in[0];
  const float* f   = (const float*)d_in[1];
  const float* Wg  = (const float*)d_in[2];
  const float* gg  = (const float*)d_in[3];
  const float* bg  = (const float*)d_in[4];
  const float* mg  = (const float*)d_in[5];
  const float* vg  = (const float*)d_in[6];
  const float* Wf  = (const float*)d_in[7];
  const float* gf  = (const float*)d_in[8];
  const float* bf_ = (const float*)d_in[9];
  const float* mf  = (const float*)d_in[10];
  const float* vf  = (const float*)d_in[11];

  char* ws = (char*)d_ws;
  u16*   Wt     = (u16*)ws;                               // 65536 B
  float* beta_f = (float*)(ws + 65536);
  float* Wgu    = (float*)(ws + 66048);
  float* Wgv    = (float*)(ws + 67584);
  float* beta_g = (float*)(ws + 69120);
  u32*   ucat   = (u32*)(ws + 69632);                     // 8 MB
  u32*   vcat   = (u32*)(ws + 69632 + 8388608);           // 8 MB
  int*   knn    = (int*)(ws + 16846848);                  // 1.376 MB
  float* out    = (float*)d_out;

  if (ws_size < (size_t)(16846848 + 16384 * KK * 4)) return;

  k_prep<<<dim3(128), dim3(256), 0, stream>>>(Wf, gf, bf_, mf, vf, Wg, gg, bg, mg, vg,
                                              Wt, beta_f, Wgu, Wgv, beta_g);
  k_geo<<<dim3(4096), dim3(256), 0, stream>>>(xyz, Wgu, Wgv, beta_g, ucat, vcat);
  k_feat<<<dim3(256), dim3(256), 0, stream>>>(f, (const u32*)Wt, beta_f, ucat, vcat);
  k_knn<<<dim3(1024), dim3(256), 0, stream>>>(xyz, knn);
  k_gather<<<dim3(256), dim3(256), 0, stream>>>(ucat, vcat, knn, out);
}